// Round 1
// baseline (613.990 us; speedup 1.0000x reference)
//
#include <hip/hip_runtime.h>
#include <hip/hip_bf16.h>
#include <math.h>

// q [8192,1024] f32, k [8192,1024] f32, v [8192,1024] f32
// scores = q@k^T; x = scores/||row|| * sqrt(8192); gated = gelu_exact(x); out = gated@v
//
// ws layout (~176 MiB):
//   [0,16M)    qb   bf16 8192x1024
//   [16M,32M)  kb   bf16 8192x1024
//   [32M,48M)  vbT  bf16 1024x8192
//   [48M,176M) scores/gated bf16 8192x8192 (in-place gelu)
//   [176M,+32K) sumsq f32 [8192]

#define MROWS 8192
#define DIN   1024
#define NBANK 8192
#define DOUT  1024

typedef float  f32x4  __attribute__((ext_vector_type(4)));
typedef __bf16 bf16x8 __attribute__((ext_vector_type(8)));

__device__ __forceinline__ float bf2f(unsigned short u) {
  union { unsigned int i; float f; } x; x.i = ((unsigned int)u) << 16; return x.f;
}
__device__ __forceinline__ unsigned short f2bf(float f) {
  union { float f; unsigned int i; } x; x.f = f;
  unsigned int u = x.i;
  unsigned int r = (u + 0x7fffu + ((u >> 16) & 1u)) >> 16;  // RNE
  return (unsigned short)r;
}

// ---------------- fp32 -> bf16 convert ----------------
__global__ void cvt_kernel(const float* __restrict__ src,
                           unsigned short* __restrict__ dst, int n) {
  int i = (blockIdx.x * 256 + threadIdx.x) * 4;
  if (i >= n) return;
  float4 vv = *(const float4*)(src + i);
  ushort4 o;
  o.x = f2bf(vv.x); o.y = f2bf(vv.y); o.z = f2bf(vv.z); o.w = f2bf(vv.w);
  *(ushort4*)(dst + i) = o;
}

// ---------------- transpose + convert: src[R][C] f32 -> dst[C][R] bf16 ----------------
__global__ void transpose_cvt_kernel(const float* __restrict__ src,
                                     unsigned short* __restrict__ dst,
                                     int R, int C) {
  __shared__ float tile[32][33];
  int c0 = blockIdx.x * 32, r0 = blockIdx.y * 32;
  for (int i = threadIdx.y; i < 32; i += 8)
    tile[i][threadIdx.x] = src[(size_t)(r0 + i) * C + c0 + threadIdx.x];
  __syncthreads();
  for (int i = threadIdx.y; i < 32; i += 8)
    dst[(size_t)(c0 + i) * R + r0 + threadIdx.x] = f2bf(tile[threadIdx.x][i]);
}

// ---------------- zero fill (float4 granularity) ----------------
__global__ void zero_f32_kernel(float* __restrict__ p, int n4) {
  int i = blockIdx.x * 256 + threadIdx.x;
  if (i < n4) ((float4*)p)[i] = make_float4(0.f, 0.f, 0.f, 0.f);
}

// ---------------- GEMM1: scores = qb @ kb^T (bf16 out) + row sumsq atomics ----------
__global__ __launch_bounds__(256, 2) void gemm1_kernel(
    const unsigned short* __restrict__ A, const unsigned short* __restrict__ B,
    unsigned short* __restrict__ C, float* __restrict__ sumsq) {
  __shared__ unsigned short As[128 * 32];
  __shared__ unsigned short Bs[128 * 32];
  const int K = DIN, ldc = NBANK;

  const int tid  = threadIdx.x;
  const int lane = tid & 63;
  const int wave = tid >> 6;
  const int wm   = (wave >> 1) * 64;
  const int wn   = (wave & 1) * 64;
  const int quad = lane >> 4;
  const int l16  = lane & 15;

  // XCD-aware bijective swizzle (T1): nwg = 64*64 = 4096, 4096 % 8 == 0.
  // XCD x (= flat % 8 under round-robin dispatch) processes 8 consecutive
  // m-tile rows -> A panels stay L2-local per XCD.
  const int flat = blockIdx.y * gridDim.x + blockIdx.x;
  const int nwg  = gridDim.x * gridDim.y;
  const int swz  = (flat & 7) * (nwg >> 3) + (flat >> 3);
  const size_t m0 = (size_t)(swz / gridDim.x) * 128;
  const size_t n0 = (size_t)(swz % gridDim.x) * 128;

  const int srow = tid >> 2;
  const int scol = (tid & 3) * 8;
  const unsigned short* Ag0 = A + (m0 + srow) * (size_t)K + scol;
  const unsigned short* Ag1 = A + (m0 + srow + 64) * (size_t)K + scol;
  const unsigned short* Bg0 = B + (n0 + srow) * (size_t)K + scol;
  const unsigned short* Bg1 = B + (n0 + srow + 64) * (size_t)K + scol;

  unsigned short* AsW0 = As + tid * 8;
  unsigned short* AsW1 = As + 64 * 32 + tid * 8;
  unsigned short* BsW0 = Bs + tid * 8;
  unsigned short* BsW1 = Bs + 64 * 32 + tid * 8;

  const unsigned short* ArP = As + (wm + l16) * 32 + quad * 8;
  const unsigned short* BrP = Bs + (wn + l16) * 32 + quad * 8;

  f32x4 acc[4][4];
#pragma unroll
  for (int i = 0; i < 4; i++)
#pragma unroll
    for (int j = 0; j < 4; j++) {
      f32x4 z = {0.f, 0.f, 0.f, 0.f};
      acc[i][j] = z;
    }

  for (int k0 = 0; k0 < K; k0 += 32) {
    __builtin_amdgcn_global_load_lds(
        (const __attribute__((address_space(1))) unsigned int*)(Ag0 + k0),
        (__attribute__((address_space(3))) unsigned int*)AsW0, 16, 0, 0);
    __builtin_amdgcn_global_load_lds(
        (const __attribute__((address_space(1))) unsigned int*)(Ag1 + k0),
        (__attribute__((address_space(3))) unsigned int*)AsW1, 16, 0, 0);
    __builtin_amdgcn_global_load_lds(
        (const __attribute__((address_space(1))) unsigned int*)(Bg0 + k0),
        (__attribute__((address_space(3))) unsigned int*)BsW0, 16, 0, 0);
    __builtin_amdgcn_global_load_lds(
        (const __attribute__((address_space(1))) unsigned int*)(Bg1 + k0),
        (__attribute__((address_space(3))) unsigned int*)BsW1, 16, 0, 0);
    __syncthreads();

    bf16x8 af[4], bfr[4];
#pragma unroll
    for (int i = 0; i < 4; i++) af[i] = *(const bf16x8*)(ArP + i * 16 * 32);
#pragma unroll
    for (int j = 0; j < 4; j++) bfr[j] = *(const bf16x8*)(BrP + j * 16 * 32);
#pragma unroll
    for (int i = 0; i < 4; i++)
#pragma unroll
      for (int j = 0; j < 4; j++)
        acc[i][j] = __builtin_amdgcn_mfma_f32_16x16x32_bf16(af[i], bfr[j],
                                                            acc[i][j], 0, 0, 0);
    __syncthreads();
  }

  // Epilogue: store bf16 scores + per-row sum-of-squares (f32 acc) via atomics.
#pragma unroll
  for (int i = 0; i < 4; i++)
#pragma unroll
    for (int r = 0; r < 4; r++) {
      size_t row = m0 + wm + i * 16 + quad * 4 + r;
      float s = 0.f;
#pragma unroll
      for (int j = 0; j < 4; j++) {
        float val = acc[i][j][r];
        s += val * val;
        C[row * (size_t)ldc + n0 + wn + j * 16 + l16] = f2bf(val);
      }
      // reduce across the 16 lanes (same quad) sharing this row
      s += __shfl_xor(s, 1);
      s += __shfl_xor(s, 2);
      s += __shfl_xor(s, 4);
      s += __shfl_xor(s, 8);
      if (l16 == 0) atomicAdd(&sumsq[row], s);
    }
}

// ---------------- in-place exact GELU(x * sqrt(N/sumsq[row])) ----------------
// finalize_scale folded in: one sqrt per thread, sumsq[row] is wave-uniform
// (8192 elems/row -> 16 waves per row). Grid-stride capped per G11.
__global__ void gelu_kernel(unsigned short* __restrict__ S,
                            const float* __restrict__ sumsq) {
  const size_t total = (size_t)MROWS * NBANK / 8;  // uint4 units
  for (size_t u = (size_t)blockIdx.x * 256 + threadIdx.x; u < total;
       u += (size_t)gridDim.x * 256) {
    size_t idx = u * 8;
    int row = (int)(idx >> 13);
    float sc = sqrtf((float)NBANK / sumsq[row]);
    uint4 vv = *(const uint4*)(S + idx);
    unsigned int w[4] = {vv.x, vv.y, vv.z, vv.w};
#pragma unroll
    for (int e = 0; e < 4; e++) {
      float x0 = bf2f((unsigned short)(w[e] & 0xffffu)) * sc;
      float x1 = bf2f((unsigned short)(w[e] >> 16)) * sc;
      float g0 = 0.5f * x0 * (1.0f + erff(x0 * 0.70710678118654752f));
      float g1 = 0.5f * x1 * (1.0f + erff(x1 * 0.70710678118654752f));
      w[e] = (unsigned int)f2bf(g0) | ((unsigned int)f2bf(g1) << 16);
    }
    uint4 o; o.x = w[0]; o.y = w[1]; o.z = w[2]; o.w = w[3];
    *(uint4*)(S + idx) = o;
  }
}

// ---------------- GEMM2: out += gated @ vbT^T, 128x256 tile, split-K x2 --------------
// 512 threads = 8 waves in 2x4 grid of 64x64 wave tiles. f32 atomic accumulate.
__global__ __launch_bounds__(512, 4) void gemm2_kernel(
    const unsigned short* __restrict__ A,   // gated [8192][8192]
    const unsigned short* __restrict__ B,   // vbT   [1024][8192]
    float* __restrict__ C) {                // out   [8192][1024], pre-zeroed
  __shared__ unsigned short As[128 * 32];   //  8 KiB
  __shared__ unsigned short Bs[256 * 32];   // 16 KiB
  const int K = NBANK, ldc = DOUT;

  const int tid  = threadIdx.x;
  const int lane = tid & 63;
  const int wave = tid >> 6;          // 0..7
  const int wm   = (wave >> 2) * 64;  // 0,64
  const int wn   = (wave & 3) * 64;   // 0,64,128,192
  const int quad = lane >> 4;
  const int l16  = lane & 15;

  // XCD swizzle within each z-slice: nwg(xy) = 4*64 = 256, 256 % 8 == 0.
  const int flat = blockIdx.y * gridDim.x + blockIdx.x;
  const int nwg  = gridDim.x * gridDim.y;
  const int swz  = (flat & 7) * (nwg >> 3) + (flat >> 3);
  const size_t m0 = (size_t)(swz / gridDim.x) * 128;
  const size_t n0 = (size_t)(swz % gridDim.x) * 256;
  const int    ks = blockIdx.z * (K / 2);   // split-K

  const int srow = tid >> 2;          // 0..127
  const int scol = (tid & 3) * 8;
  const unsigned short* Ag  = A + (m0 + srow) * (size_t)K + scol + ks;
  const unsigned short* Bg0 = B + (n0 + srow) * (size_t)K + scol + ks;
  const unsigned short* Bg1 = B + (n0 + srow + 128) * (size_t)K + scol + ks;

  unsigned short* AsW  = As + tid * 8;
  unsigned short* BsW0 = Bs + tid * 8;
  unsigned short* BsW1 = Bs + 512 * 8 + tid * 8;

  const unsigned short* ArP = As + (wm + l16) * 32 + quad * 8;
  const unsigned short* BrP = Bs + (wn + l16) * 32 + quad * 8;

  f32x4 acc[4][4];
#pragma unroll
  for (int i = 0; i < 4; i++)
#pragma unroll
    for (int j = 0; j < 4; j++) {
      f32x4 z = {0.f, 0.f, 0.f, 0.f};
      acc[i][j] = z;
    }

  for (int k0 = 0; k0 < K / 2; k0 += 32) {
    __builtin_amdgcn_global_load_lds(
        (const __attribute__((address_space(1))) unsigned int*)(Ag + k0),
        (__attribute__((address_space(3))) unsigned int*)AsW, 16, 0, 0);
    __builtin_amdgcn_global_load_lds(
        (const __attribute__((address_space(1))) unsigned int*)(Bg0 + k0),
        (__attribute__((address_space(3))) unsigned int*)BsW0, 16, 0, 0);
    __builtin_amdgcn_global_load_lds(
        (const __attribute__((address_space(1))) unsigned int*)(Bg1 + k0),
        (__attribute__((address_space(3))) unsigned int*)BsW1, 16, 0, 0);
    __syncthreads();

    bf16x8 af[4], bfr[4];
#pragma unroll
    for (int i = 0; i < 4; i++) af[i] = *(const bf16x8*)(ArP + i * 16 * 32);
#pragma unroll
    for (int j = 0; j < 4; j++) bfr[j] = *(const bf16x8*)(BrP + j * 16 * 32);
#pragma unroll
    for (int i = 0; i < 4; i++)
#pragma unroll
      for (int j = 0; j < 4; j++)
        acc[i][j] = __builtin_amdgcn_mfma_f32_16x16x32_bf16(af[i], bfr[j],
                                                            acc[i][j], 0, 0, 0);
    __syncthreads();
  }

#pragma unroll
  for (int i = 0; i < 4; i++)
#pragma unroll
    for (int j = 0; j < 4; j++)
#pragma unroll
      for (int r = 0; r < 4; r++) {
        size_t row = m0 + wm + i * 16 + quad * 4 + r;
        size_t col = n0 + wn + j * 16 + l16;
        atomicAdd(&C[row * (size_t)ldc + col], acc[i][j][r]);
      }
}

extern "C" void kernel_launch(void* const* d_in, const int* in_sizes, int n_in,
                              void* d_out, int out_size, void* d_ws, size_t ws_size,
                              hipStream_t stream) {
  const float* q = (const float*)d_in[0];
  const float* k = (const float*)d_in[1];
  const float* v = (const float*)d_in[2];
  float* out = (float*)d_out;

  char* ws = (char*)d_ws;
  const size_t MB = 1024ull * 1024ull;
  unsigned short* qb     = (unsigned short*)(ws);
  unsigned short* kb     = (unsigned short*)(ws + 16 * MB);
  unsigned short* vbT    = (unsigned short*)(ws + 32 * MB);
  unsigned short* scores = (unsigned short*)(ws + 48 * MB);
  float*          scale  = (float*)(ws + 176 * MB);  // sumsq

  const int nqk = MROWS * DIN;

  // zero out (atomic accumulate target) and sumsq
  zero_f32_kernel<<<(MROWS * DOUT / 4 + 255) / 256, 256, 0, stream>>>(out,
                                                                      MROWS * DOUT / 4);
  zero_f32_kernel<<<(MROWS / 4 + 255) / 256, 256, 0, stream>>>(scale, MROWS / 4);

  cvt_kernel<<<nqk / 1024, 256, 0, stream>>>(q, qb, nqk);
  cvt_kernel<<<nqk / 1024, 256, 0, stream>>>(k, kb, nqk);
  transpose_cvt_kernel<<<dim3(DOUT / 32, NBANK / 32), dim3(32, 8), 0, stream>>>(
      v, vbT, NBANK, DOUT);

  gemm1_kernel<<<dim3(NBANK / 128, MROWS / 128), 256, 0, stream>>>(qb, kb, scores,
                                                                   scale);

  // scale finalize folded into gelu; grid-stride capped at 4096 blocks (G11)
  gelu_kernel<<<4096, 256, 0, stream>>>(scores, scale);

  gemm2_kernel<<<dim3(DOUT / 256, MROWS / 128, 2), 512, 0, stream>>>(scores, vbT, out);
}

// Round 2
// 575.416 us; speedup vs baseline: 1.0670x; 1.0670x over previous
//
#include <hip/hip_runtime.h>
#include <hip/hip_bf16.h>
#include <math.h>

// q [8192,1024] f32, k [8192,1024] f32, v [8192,1024] f32
// scores = q@k^T; x = scores/||row|| * sqrt(8192); gated = gelu_exact(x); out = gated@v
//
// ws layout (~176 MiB):
//   [0,16M)    qb   bf16 8192x1024
//   [16M,32M)  kb   bf16 8192x1024
//   [32M,48M)  vbT  bf16 1024x8192
//   [48M,176M) scores/gated bf16 8192x8192 (in-place gelu)
//   [176M,+32K) sumsq f32 [8192]

#define MROWS 8192
#define DIN   1024
#define NBANK 8192
#define DOUT  1024

typedef float  f32x4  __attribute__((ext_vector_type(4)));
typedef __bf16 bf16x8 __attribute__((ext_vector_type(8)));

__device__ __forceinline__ float bf2f(unsigned short u) {
  union { unsigned int i; float f; } x; x.i = ((unsigned int)u) << 16; return x.f;
}
__device__ __forceinline__ unsigned short f2bf(float f) {
  union { float f; unsigned int i; } x; x.f = f;
  unsigned int u = x.i;
  unsigned int r = (u + 0x7fffu + ((u >> 16) & 1u)) >> 16;  // RNE
  return (unsigned short)r;
}

// ---------------- fp32 -> bf16 convert ----------------
__global__ void cvt_kernel(const float* __restrict__ src,
                           unsigned short* __restrict__ dst, int n) {
  int i = (blockIdx.x * 256 + threadIdx.x) * 4;
  if (i >= n) return;
  float4 vv = *(const float4*)(src + i);
  ushort4 o;
  o.x = f2bf(vv.x); o.y = f2bf(vv.y); o.z = f2bf(vv.z); o.w = f2bf(vv.w);
  *(ushort4*)(dst + i) = o;
}

// ---------------- transpose + convert: src[R][C] f32 -> dst[C][R] bf16 ----------------
__global__ void transpose_cvt_kernel(const float* __restrict__ src,
                                     unsigned short* __restrict__ dst,
                                     int R, int C) {
  __shared__ float tile[32][33];
  int c0 = blockIdx.x * 32, r0 = blockIdx.y * 32;
  for (int i = threadIdx.y; i < 32; i += 8)
    tile[i][threadIdx.x] = src[(size_t)(r0 + i) * C + c0 + threadIdx.x];
  __syncthreads();
  for (int i = threadIdx.y; i < 32; i += 8)
    dst[(size_t)(c0 + i) * R + r0 + threadIdx.x] = f2bf(tile[threadIdx.x][i]);
}

// ---------------- zero fill (float4 granularity) ----------------
__global__ void zero_f32_kernel(float* __restrict__ p, int n4) {
  int i = blockIdx.x * 256 + threadIdx.x;
  if (i < n4) ((float4*)p)[i] = make_float4(0.f, 0.f, 0.f, 0.f);
}

// ============================================================================
// 256x256 8-phase GEMM core (plain-HIP port of the m201 template).
// 512 threads = 8 waves (2M x 4N); per-wave output 128x64; BK=64.
// LDS: A,B each 2 buffers x (2 K-half sub-buffers of [256 rows][32 cols] bf16)
//      = 2*32KB + 2*32KB = 128 KiB. 64B row stride -> b128 frag reads hit
//      bank-group (4r+q)&7 uniformly: conflict-free, no swizzle needed, so
//      global_load_lds staging stays linear (rule 21).
// Waits: vmcnt(4) twice per K-tile (2 half-tiles = 4 loads stay in flight);
//        drains to vmcnt(0) only on the last tile. setprio(1) around MFMA.
// ============================================================================

__device__ __forceinline__ void stage_half(const unsigned short* src, int ld,
                                           unsigned short* dstbase, int tid) {
  // 2 x global_load_lds dwordx4: rows (tid>>2) and (tid>>2)+128, 16B each.
  __builtin_amdgcn_global_load_lds(
      (const __attribute__((address_space(1))) unsigned int*)src,
      (__attribute__((address_space(3))) unsigned int*)(dstbase + tid * 8), 16, 0, 0);
  __builtin_amdgcn_global_load_lds(
      (const __attribute__((address_space(1))) unsigned int*)(src + (size_t)128 * ld),
      (__attribute__((address_space(3))) unsigned int*)(dstbase + 4096 + tid * 8), 16,
      0, 0);
}

__device__ __forceinline__ void read4(const unsigned short* base, bf16x8 f[4]) {
#pragma unroll
  for (int i = 0; i < 4; ++i) f[i] = *(const bf16x8*)(base + i * 512);
}

__device__ __forceinline__ void mfma16(const bf16x8 a[4], const bf16x8 b[4],
                                       f32x4 (&acc)[8][4], int mh) {
#pragma unroll
  for (int m = 0; m < 4; ++m)
#pragma unroll
    for (int n = 0; n < 4; ++n)
      acc[mh * 4 + m][n] = __builtin_amdgcn_mfma_f32_16x16x32_bf16(
          a[m], b[n], acc[mh * 4 + m][n], 0, 0, 0);
}

// Ap: A tile base (row-major, lda), rows m0..m0+255, k contiguous.
// Bp: B tile base (row-major, ldb), rows n0..n0+255 (B^T layout), k contiguous.
__device__ __forceinline__ void gemm_core(const unsigned short* __restrict__ Ap,
                                          const unsigned short* __restrict__ Bp,
                                          int lda, int ldb, int nkt,
                                          unsigned short* As, unsigned short* Bs,
                                          f32x4 (&acc)[8][4]) {
  const int tid  = threadIdx.x;
  const int lane = tid & 63;
  const int wm   = (tid >> 6) >> 2;  // 0..1
  const int wn   = (tid >> 6) & 3;   // 0..3
  const int quad = lane >> 4;
  const int l16  = lane & 15;
  // frag read offsets within a 16KB K-half sub-buffer (ushort units)
  const int aoff = (wm * 128 + l16) * 32 + quad * 8;
  const int boff = (wn * 64 + l16) * 32 + quad * 8;

  // per-thread staging source base: row tid>>2, 16B chunk tid&3
  const unsigned short* Ag = Ap + (size_t)(tid >> 2) * lda + (tid & 3) * 8;
  const unsigned short* Bg = Bp + (size_t)(tid >> 2) * ldb + (tid & 3) * 8;

#pragma unroll
  for (int i = 0; i < 8; ++i)
#pragma unroll
    for (int j = 0; j < 4; ++j) {
      f32x4 z = {0.f, 0.f, 0.f, 0.f};
      acc[i][j] = z;
    }

  // Prologue: stage tile 0 (A-k0, B-k0, A-k1, B-k1) into buffer 0.
  stage_half(Ag, lda, As, tid);
  stage_half(Bg, ldb, Bs, tid);
  stage_half(Ag + 32, lda, As + 8192, tid);
  stage_half(Bg + 32, ldb, Bs + 8192, tid);
  asm volatile("s_waitcnt vmcnt(4)" ::: "memory");  // k0 halves landed
  __builtin_amdgcn_s_barrier();

  for (int kt = 0; kt < nkt; ++kt) {
    const int cur = kt & 1, nx = cur ^ 1;
    const unsigned short* Ab = As + cur * 16384;
    const unsigned short* Bb = Bs + cur * 16384;
    unsigned short* Asn = As + nx * 16384;
    unsigned short* Bsn = Bs + nx * 16384;
    const bool pf = (kt + 1 < nkt);
    const int knext = (kt + 1) * 64;
    bf16x8 a[4], b[4];

    // ---- P0: (mh0, ks0) ----
    read4(Ab + aoff, a);
    read4(Bb + boff, b);
    if (pf) stage_half(Ag + knext, lda, Asn, tid);
    __builtin_amdgcn_s_barrier();
    asm volatile("s_waitcnt lgkmcnt(0)" ::: "memory");
    __builtin_amdgcn_sched_barrier(0);
    __builtin_amdgcn_s_setprio(1);
    mfma16(a, b, acc, 0);
    __builtin_amdgcn_s_setprio(0);
    __builtin_amdgcn_s_barrier();

    // ---- P1: (mh1, ks0) ----
    read4(Ab + aoff + 2048, a);
    if (pf) stage_half(Bg + knext, ldb, Bsn, tid);
    __builtin_amdgcn_s_barrier();
    asm volatile("s_waitcnt lgkmcnt(0)" ::: "memory");
    __builtin_amdgcn_sched_barrier(0);
    __builtin_amdgcn_s_setprio(1);
    mfma16(a, b, acc, 1);
    __builtin_amdgcn_s_setprio(0);
    if (pf)
      asm volatile("s_waitcnt vmcnt(4)" ::: "memory");  // this tile's k1 landed
    else
      asm volatile("s_waitcnt vmcnt(0)" ::: "memory");
    __builtin_amdgcn_s_barrier();

    // ---- P2: (mh1, ks1) ----
    read4(Ab + 8192 + aoff + 2048, a);
    read4(Bb + 8192 + boff, b);
    if (pf) stage_half(Ag + knext + 32, lda, Asn + 8192, tid);
    __builtin_amdgcn_s_barrier();
    asm volatile("s_waitcnt lgkmcnt(0)" ::: "memory");
    __builtin_amdgcn_sched_barrier(0);
    __builtin_amdgcn_s_setprio(1);
    mfma16(a, b, acc, 1);
    __builtin_amdgcn_s_setprio(0);
    __builtin_amdgcn_s_barrier();

    // ---- P3: (mh0, ks1) ----
    read4(Ab + 8192 + aoff, a);
    if (pf) stage_half(Bg + knext + 32, ldb, Bsn + 8192, tid);
    __builtin_amdgcn_s_barrier();
    asm volatile("s_waitcnt lgkmcnt(0)" ::: "memory");
    __builtin_amdgcn_sched_barrier(0);
    __builtin_amdgcn_s_setprio(1);
    mfma16(a, b, acc, 0);
    __builtin_amdgcn_s_setprio(0);
    if (pf) asm volatile("s_waitcnt vmcnt(4)" ::: "memory");  // next tile's k0 landed
    __builtin_amdgcn_s_barrier();
  }
}

// ---------------- GEMM1: scores = qb @ kb^T (bf16 out) + row sumsq atomics ----------
__global__ __launch_bounds__(512) void gemm1_kernel(
    const unsigned short* __restrict__ A, const unsigned short* __restrict__ B,
    unsigned short* __restrict__ C, float* __restrict__ sumsq) {
  __shared__ unsigned short As[2 * 16384];  // 64 KiB
  __shared__ unsigned short Bs[2 * 16384];  // 64 KiB

  // XCD-aware bijective swizzle: nwg = 32*32 = 1024, %8 == 0.
  const int flat = blockIdx.y * gridDim.x + blockIdx.x;
  const int nwg  = gridDim.x * gridDim.y;
  const int swz  = (flat & 7) * (nwg >> 3) + (flat >> 3);
  const size_t m0 = (size_t)(swz / gridDim.x) * 256;
  const size_t n0 = (size_t)(swz % gridDim.x) * 256;

  f32x4 acc[8][4];
  gemm_core(A + m0 * DIN, B + n0 * DIN, DIN, DIN, DIN / 64, As, Bs, acc);

  const int tid  = threadIdx.x;
  const int lane = tid & 63;
  const int wm   = (tid >> 6) >> 2;
  const int wn   = (tid >> 6) & 3;
  const int quad = lane >> 4;
  const int l16  = lane & 15;

#pragma unroll
  for (int mf = 0; mf < 8; ++mf)
#pragma unroll
    for (int r = 0; r < 4; ++r) {
      size_t row = m0 + wm * 128 + mf * 16 + quad * 4 + r;
      float s = 0.f;
#pragma unroll
      for (int nf = 0; nf < 4; ++nf) {
        float val = acc[mf][nf][r];
        s += val * val;
        C[row * (size_t)NBANK + n0 + wn * 64 + nf * 16 + l16] = f2bf(val);
      }
      // reduce across the 16 lanes (same quad) sharing this row
      s += __shfl_xor(s, 1);
      s += __shfl_xor(s, 2);
      s += __shfl_xor(s, 4);
      s += __shfl_xor(s, 8);
      if (l16 == 0) atomicAdd(&sumsq[row], s);
    }
}

// ---------------- in-place exact GELU(x * sqrt(N/sumsq[row])) ----------------
__global__ void gelu_kernel(unsigned short* __restrict__ S,
                            const float* __restrict__ sumsq) {
  const size_t total = (size_t)MROWS * NBANK / 8;  // uint4 units
  for (size_t u = (size_t)blockIdx.x * 256 + threadIdx.x; u < total;
       u += (size_t)gridDim.x * 256) {
    size_t idx = u * 8;
    int row = (int)(idx >> 13);
    float sc = sqrtf((float)NBANK / sumsq[row]);
    uint4 vv = *(const uint4*)(S + idx);
    unsigned int w[4] = {vv.x, vv.y, vv.z, vv.w};
#pragma unroll
    for (int e = 0; e < 4; e++) {
      float x0 = bf2f((unsigned short)(w[e] & 0xffffu)) * sc;
      float x1 = bf2f((unsigned short)(w[e] >> 16)) * sc;
      float g0 = 0.5f * x0 * (1.0f + erff(x0 * 0.70710678118654752f));
      float g1 = 0.5f * x1 * (1.0f + erff(x1 * 0.70710678118654752f));
      w[e] = (unsigned int)f2bf(g0) | ((unsigned int)f2bf(g1) << 16);
    }
    uint4 o; o.x = w[0]; o.y = w[1]; o.z = w[2]; o.w = w[3];
    *(uint4*)(S + idx) = o;
  }
}

// ---------------- GEMM2: out += gated @ vbT^T, 256x256 tile, split-K x2 -------------
__global__ __launch_bounds__(512) void gemm2_kernel(
    const unsigned short* __restrict__ A,   // gated [8192][8192]
    const unsigned short* __restrict__ B,   // vbT   [1024][8192]
    float* __restrict__ C) {                // out   [8192][1024], pre-zeroed
  __shared__ unsigned short As[2 * 16384];
  __shared__ unsigned short Bs[2 * 16384];

  // per-z swizzle: nwg(xy) = 4*32 = 128, %8 == 0.
  const int flat = blockIdx.y * gridDim.x + blockIdx.x;
  const int nwg  = gridDim.x * gridDim.y;
  const int swz  = (flat & 7) * (nwg >> 3) + (flat >> 3);
  const size_t m0 = (size_t)(swz / gridDim.x) * 256;
  const size_t n0 = (size_t)(swz % gridDim.x) * 256;
  const int kbase = blockIdx.z * (NBANK / 2);  // split-K

  f32x4 acc[8][4];
  gemm_core(A + m0 * (size_t)NBANK + kbase, B + n0 * (size_t)NBANK + kbase, NBANK,
            NBANK, (NBANK / 2) / 64, As, Bs, acc);

  const int tid  = threadIdx.x;
  const int lane = tid & 63;
  const int wm   = (tid >> 6) >> 2;
  const int wn   = (tid >> 6) & 3;
  const int quad = lane >> 4;
  const int l16  = lane & 15;

#pragma unroll
  for (int mf = 0; mf < 8; ++mf)
#pragma unroll
    for (int nf = 0; nf < 4; ++nf)
#pragma unroll
      for (int r = 0; r < 4; ++r) {
        size_t row = m0 + wm * 128 + mf * 16 + quad * 4 + r;
        size_t col = n0 + wn * 64 + nf * 16 + l16;
        atomicAdd(&C[row * (size_t)DOUT + col], acc[mf][nf][r]);
      }
}

extern "C" void kernel_launch(void* const* d_in, const int* in_sizes, int n_in,
                              void* d_out, int out_size, void* d_ws, size_t ws_size,
                              hipStream_t stream) {
  const float* q = (const float*)d_in[0];
  const float* k = (const float*)d_in[1];
  const float* v = (const float*)d_in[2];
  float* out = (float*)d_out;

  char* ws = (char*)d_ws;
  const size_t MB = 1024ull * 1024ull;
  unsigned short* qb     = (unsigned short*)(ws);
  unsigned short* kb     = (unsigned short*)(ws + 16 * MB);
  unsigned short* vbT    = (unsigned short*)(ws + 32 * MB);
  unsigned short* scores = (unsigned short*)(ws + 48 * MB);
  float*          scale  = (float*)(ws + 176 * MB);  // sumsq

  const int nqk = MROWS * DIN;

  // zero out (atomic accumulate target) and sumsq
  zero_f32_kernel<<<(MROWS * DOUT / 4 + 255) / 256, 256, 0, stream>>>(out,
                                                                      MROWS * DOUT / 4);
  zero_f32_kernel<<<(MROWS / 4 + 255) / 256, 256, 0, stream>>>(scale, MROWS / 4);

  cvt_kernel<<<nqk / 1024, 256, 0, stream>>>(q, qb, nqk);
  cvt_kernel<<<nqk / 1024, 256, 0, stream>>>(k, kb, nqk);
  transpose_cvt_kernel<<<dim3(DOUT / 32, NBANK / 32), dim3(32, 8), 0, stream>>>(
      v, vbT, NBANK, DOUT);

  gemm1_kernel<<<dim3(NBANK / 256, MROWS / 256), 512, 0, stream>>>(qb, kb, scores,
                                                                   scale);

  gelu_kernel<<<4096, 256, 0, stream>>>(scores, scale);

  gemm2_kernel<<<dim3(DOUT / 256, MROWS / 256, 2), 512, 0, stream>>>(scores, vbT, out);
}

// Round 4
// 544.278 us; speedup vs baseline: 1.1281x; 1.0572x over previous
//
#include <hip/hip_runtime.h>
#include <hip/hip_bf16.h>
#include <math.h>

// q [8192,1024] f32, k [8192,1024] f32, v [8192,1024] f32
// scores = q@k^T; x = scores/||row|| * sqrt(8192); gated = gelu_exact(x); out = gated@v
//
// ws layout (~176 MiB):
//   [0,16M)    qb   bf16 8192x1024
//   [16M,32M)  kb   bf16 8192x1024
//   [32M,48M)  vbT  bf16 1024x8192
//   [48M,176M) scores/gated bf16 8192x8192 (in-place gelu)
//   [176M,+32K) sumsq f32 [8192]

#define MROWS 8192
#define DIN   1024
#define NBANK 8192
#define DOUT  1024

typedef float  f32x4  __attribute__((ext_vector_type(4)));
typedef __bf16 bf16x8 __attribute__((ext_vector_type(8)));

__device__ __forceinline__ float bf2f(unsigned short u) {
  union { unsigned int i; float f; } x; x.i = ((unsigned int)u) << 16; return x.f;
}
__device__ __forceinline__ unsigned short f2bf(float f) {
  union { float f; unsigned int i; } x; x.f = f;
  unsigned int u = x.i;
  unsigned int r = (u + 0x7fffu + ((u >> 16) & 1u)) >> 16;  // RNE
  return (unsigned short)r;
}

// ---------------- fp32 -> bf16 convert ----------------
__global__ void cvt_kernel(const float* __restrict__ src,
                           unsigned short* __restrict__ dst, int n) {
  int i = (blockIdx.x * 256 + threadIdx.x) * 4;
  if (i >= n) return;
  float4 vv = *(const float4*)(src + i);
  ushort4 o;
  o.x = f2bf(vv.x); o.y = f2bf(vv.y); o.z = f2bf(vv.z); o.w = f2bf(vv.w);
  *(ushort4*)(dst + i) = o;
}

// ---------------- transpose + convert: src[R][C] f32 -> dst[C][R] bf16 ----------------
__global__ void transpose_cvt_kernel(const float* __restrict__ src,
                                     unsigned short* __restrict__ dst,
                                     int R, int C) {
  __shared__ float tile[32][33];
  int c0 = blockIdx.x * 32, r0 = blockIdx.y * 32;
  for (int i = threadIdx.y; i < 32; i += 8)
    tile[i][threadIdx.x] = src[(size_t)(r0 + i) * C + c0 + threadIdx.x];
  __syncthreads();
  for (int i = threadIdx.y; i < 32; i += 8)
    dst[(size_t)(c0 + i) * R + r0 + threadIdx.x] = f2bf(tile[threadIdx.x][i]);
}

// ---------------- zero fill (float4 granularity) ----------------
__global__ void zero_f32_kernel(float* __restrict__ p, int n4) {
  int i = blockIdx.x * 256 + threadIdx.x;
  if (i < n4) ((float4*)p)[i] = make_float4(0.f, 0.f, 0.f, 0.f);
}

// ============================================================================
// 256x256 8-phase GEMM core (unchanged: gemm1 control arm).
// ============================================================================

__device__ __forceinline__ void stage_half(const unsigned short* src, int ld,
                                           unsigned short* dstbase, int tid) {
  __builtin_amdgcn_global_load_lds(
      (const __attribute__((address_space(1))) unsigned int*)src,
      (__attribute__((address_space(3))) unsigned int*)(dstbase + tid * 8), 16, 0, 0);
  __builtin_amdgcn_global_load_lds(
      (const __attribute__((address_space(1))) unsigned int*)(src + (size_t)128 * ld),
      (__attribute__((address_space(3))) unsigned int*)(dstbase + 4096 + tid * 8), 16,
      0, 0);
}

__device__ __forceinline__ void read4(const unsigned short* base, bf16x8 f[4]) {
#pragma unroll
  for (int i = 0; i < 4; ++i) f[i] = *(const bf16x8*)(base + i * 512);
}

__device__ __forceinline__ void mfma16(const bf16x8 a[4], const bf16x8 b[4],
                                       f32x4 (&acc)[8][4], int mh) {
#pragma unroll
  for (int m = 0; m < 4; ++m)
#pragma unroll
    for (int n = 0; n < 4; ++n)
      acc[mh * 4 + m][n] = __builtin_amdgcn_mfma_f32_16x16x32_bf16(
          a[m], b[n], acc[mh * 4 + m][n], 0, 0, 0);
}

__device__ __forceinline__ void gemm_core(const unsigned short* __restrict__ Ap,
                                          const unsigned short* __restrict__ Bp,
                                          int lda, int ldb, int nkt,
                                          unsigned short* As, unsigned short* Bs,
                                          f32x4 (&acc)[8][4]) {
  const int tid  = threadIdx.x;
  const int lane = tid & 63;
  const int wm   = (tid >> 6) >> 2;  // 0..1
  const int wn   = (tid >> 6) & 3;   // 0..3
  const int quad = lane >> 4;
  const int l16  = lane & 15;
  const int aoff = (wm * 128 + l16) * 32 + quad * 8;
  const int boff = (wn * 64 + l16) * 32 + quad * 8;

  const unsigned short* Ag = Ap + (size_t)(tid >> 2) * lda + (tid & 3) * 8;
  const unsigned short* Bg = Bp + (size_t)(tid >> 2) * ldb + (tid & 3) * 8;

#pragma unroll
  for (int i = 0; i < 8; ++i)
#pragma unroll
    for (int j = 0; j < 4; ++j) {
      f32x4 z = {0.f, 0.f, 0.f, 0.f};
      acc[i][j] = z;
    }

  stage_half(Ag, lda, As, tid);
  stage_half(Bg, ldb, Bs, tid);
  stage_half(Ag + 32, lda, As + 8192, tid);
  stage_half(Bg + 32, ldb, Bs + 8192, tid);
  asm volatile("s_waitcnt vmcnt(4)" ::: "memory");
  __builtin_amdgcn_s_barrier();

  for (int kt = 0; kt < nkt; ++kt) {
    const int cur = kt & 1, nx = cur ^ 1;
    const unsigned short* Ab = As + cur * 16384;
    const unsigned short* Bb = Bs + cur * 16384;
    unsigned short* Asn = As + nx * 16384;
    unsigned short* Bsn = Bs + nx * 16384;
    const bool pf = (kt + 1 < nkt);
    const int knext = (kt + 1) * 64;
    bf16x8 a[4], b[4];

    // ---- P0: (mh0, ks0) ----
    read4(Ab + aoff, a);
    read4(Bb + boff, b);
    if (pf) stage_half(Ag + knext, lda, Asn, tid);
    __builtin_amdgcn_s_barrier();
    asm volatile("s_waitcnt lgkmcnt(0)" ::: "memory");
    __builtin_amdgcn_sched_barrier(0);
    __builtin_amdgcn_s_setprio(1);
    mfma16(a, b, acc, 0);
    __builtin_amdgcn_s_setprio(0);
    __builtin_amdgcn_s_barrier();

    // ---- P1: (mh1, ks0) ----
    read4(Ab + aoff + 2048, a);
    if (pf) stage_half(Bg + knext, ldb, Bsn, tid);
    __builtin_amdgcn_s_barrier();
    asm volatile("s_waitcnt lgkmcnt(0)" ::: "memory");
    __builtin_amdgcn_sched_barrier(0);
    __builtin_amdgcn_s_setprio(1);
    mfma16(a, b, acc, 1);
    __builtin_amdgcn_s_setprio(0);
    if (pf)
      asm volatile("s_waitcnt vmcnt(4)" ::: "memory");
    else
      asm volatile("s_waitcnt vmcnt(0)" ::: "memory");
    __builtin_amdgcn_s_barrier();

    // ---- P2: (mh1, ks1) ----
    read4(Ab + 8192 + aoff + 2048, a);
    read4(Bb + 8192 + boff, b);
    if (pf) stage_half(Ag + knext + 32, lda, Asn + 8192, tid);
    __builtin_amdgcn_s_barrier();
    asm volatile("s_waitcnt lgkmcnt(0)" ::: "memory");
    __builtin_amdgcn_sched_barrier(0);
    __builtin_amdgcn_s_setprio(1);
    mfma16(a, b, acc, 1);
    __builtin_amdgcn_s_setprio(0);
    __builtin_amdgcn_s_barrier();

    // ---- P3: (mh0, ks1) ----
    read4(Ab + 8192 + aoff, a);
    if (pf) stage_half(Bg + knext + 32, ldb, Bsn + 8192, tid);
    __builtin_amdgcn_s_barrier();
    asm volatile("s_waitcnt lgkmcnt(0)" ::: "memory");
    __builtin_amdgcn_sched_barrier(0);
    __builtin_amdgcn_s_setprio(1);
    mfma16(a, b, acc, 0);
    __builtin_amdgcn_s_setprio(0);
    if (pf) asm volatile("s_waitcnt vmcnt(4)" ::: "memory");
    __builtin_amdgcn_s_barrier();
  }
}

// ---------------- GEMM1: scores = qb @ kb^T (bf16 out) + row sumsq atomics ----------
__global__ __launch_bounds__(512) void gemm1_kernel(
    const unsigned short* __restrict__ A, const unsigned short* __restrict__ B,
    unsigned short* __restrict__ C, float* __restrict__ sumsq) {
  __shared__ unsigned short As[2 * 16384];
  __shared__ unsigned short Bs[2 * 16384];

  const int flat = blockIdx.y * gridDim.x + blockIdx.x;
  const int nwg  = gridDim.x * gridDim.y;
  const int swz  = (flat & 7) * (nwg >> 3) + (flat >> 3);
  const size_t m0 = (size_t)(swz / gridDim.x) * 256;
  const size_t n0 = (size_t)(swz % gridDim.x) * 256;

  f32x4 acc[8][4];
  gemm_core(A + m0 * DIN, B + n0 * DIN, DIN, DIN, DIN / 64, As, Bs, acc);

  const int tid  = threadIdx.x;
  const int lane = tid & 63;
  const int wm   = (tid >> 6) >> 2;
  const int wn   = (tid >> 6) & 3;
  const int quad = lane >> 4;
  const int l16  = lane & 15;

#pragma unroll
  for (int mf = 0; mf < 8; ++mf)
#pragma unroll
    for (int r = 0; r < 4; ++r) {
      size_t row = m0 + wm * 128 + mf * 16 + quad * 4 + r;
      float s = 0.f;
#pragma unroll
      for (int nf = 0; nf < 4; ++nf) {
        float val = acc[mf][nf][r];
        s += val * val;
        C[row * (size_t)NBANK + n0 + wn * 64 + nf * 16 + l16] = f2bf(val);
      }
      s += __shfl_xor(s, 1);
      s += __shfl_xor(s, 2);
      s += __shfl_xor(s, 4);
      s += __shfl_xor(s, 8);
      if (l16 == 0) atomicAdd(&sumsq[row], s);
    }
}

// ---------------- in-place exact GELU(x * sqrt(N/sumsq[row])) ----------------
__global__ void gelu_kernel(unsigned short* __restrict__ S,
                            const float* __restrict__ sumsq) {
  const size_t total = (size_t)MROWS * NBANK / 8;  // uint4 units
  for (size_t u = (size_t)blockIdx.x * 256 + threadIdx.x; u < total;
       u += (size_t)gridDim.x * 256) {
    size_t idx = u * 8;
    int row = (int)(idx >> 13);
    float sc = sqrtf((float)NBANK / sumsq[row]);
    uint4 vv = *(const uint4*)(S + idx);
    unsigned int w[4] = {vv.x, vv.y, vv.z, vv.w};
#pragma unroll
    for (int e = 0; e < 4; e++) {
      float x0 = bf2f((unsigned short)(w[e] & 0xffffu)) * sc;
      float x1 = bf2f((unsigned short)(w[e] >> 16)) * sc;
      float g0 = 0.5f * x0 * (1.0f + erff(x0 * 0.70710678118654752f));
      float g1 = 0.5f * x1 * (1.0f + erff(x1 * 0.70710678118654752f));
      w[e] = (unsigned int)f2bf(g0) | ((unsigned int)f2bf(g1) << 16);
    }
    uint4 o; o.x = w[0]; o.y = w[1]; o.z = w[2]; o.w = w[3];
    *(uint4*)(S + idx) = o;
  }
}

// ---------------- GEMM2: out = gated @ vbT^T, 128x128 tile, NO split-K --------------
// m97-class structure: 256 thr = 4 waves (2x2 of 64x64), BK=32, 16 KiB LDS,
// 4 blocks/CU (cross-block TLP hides the syncthreads drain), plain f32 stores
// (no atomics, no pre-zero). Grid 8x64 = 512 blocks; XCD swizzle gives each
// XCD 8 m-panels x 8 n-panels -> A panels reused 8x inside one XCD's L2.
__global__ __launch_bounds__(256, 4) void gemm2_kernel(
    const unsigned short* __restrict__ A,   // gated [8192][8192]
    const unsigned short* __restrict__ B,   // vbT   [1024][8192]
    float* __restrict__ C) {                // out   [8192][1024]
  __shared__ unsigned short As[128 * 32];
  __shared__ unsigned short Bs[128 * 32];
  const int K = NBANK, ldc = DOUT;

  const int tid  = threadIdx.x;
  const int lane = tid & 63;
  const int wave = tid >> 6;
  const int wm   = (wave >> 1) * 64;
  const int wn   = (wave & 1) * 64;
  const int quad = lane >> 4;
  const int l16  = lane & 15;

  // XCD swizzle: nwg = 8*64 = 512, %8==0.
  const int flat = blockIdx.y * gridDim.x + blockIdx.x;
  const int nwg  = gridDim.x * gridDim.y;
  const int swz  = (flat & 7) * (nwg >> 3) + (flat >> 3);
  const size_t m0 = (size_t)(swz / gridDim.x) * 128;
  const size_t n0 = (size_t)(swz % gridDim.x) * 128;

  const int srow = tid >> 2;
  const int scol = (tid & 3) * 8;
  const unsigned short* Ag0 = A + (m0 + srow) * (size_t)K + scol;
  const unsigned short* Ag1 = A + (m0 + srow + 64) * (size_t)K + scol;
  const unsigned short* Bg0 = B + (n0 + srow) * (size_t)K + scol;
  const unsigned short* Bg1 = B + (n0 + srow + 64) * (size_t)K + scol;

  unsigned short* AsW0 = As + tid * 8;
  unsigned short* AsW1 = As + 64 * 32 + tid * 8;
  unsigned short* BsW0 = Bs + tid * 8;
  unsigned short* BsW1 = Bs + 64 * 32 + tid * 8;

  const unsigned short* ArP = As + (wm + l16) * 32 + quad * 8;
  const unsigned short* BrP = Bs + (wn + l16) * 32 + quad * 8;

  f32x4 acc[4][4];
#pragma unroll
  for (int i = 0; i < 4; i++)
#pragma unroll
    for (int j = 0; j < 4; j++) {
      f32x4 z = {0.f, 0.f, 0.f, 0.f};
      acc[i][j] = z;
    }

  for (int k0 = 0; k0 < K; k0 += 32) {
    __builtin_amdgcn_global_load_lds(
        (const __attribute__((address_space(1))) unsigned int*)(Ag0 + k0),
        (__attribute__((address_space(3))) unsigned int*)AsW0, 16, 0, 0);
    __builtin_amdgcn_global_load_lds(
        (const __attribute__((address_space(1))) unsigned int*)(Ag1 + k0),
        (__attribute__((address_space(3))) unsigned int*)AsW1, 16, 0, 0);
    __builtin_amdgcn_global_load_lds(
        (const __attribute__((address_space(1))) unsigned int*)(Bg0 + k0),
        (__attribute__((address_space(3))) unsigned int*)BsW0, 16, 0, 0);
    __builtin_amdgcn_global_load_lds(
        (const __attribute__((address_space(1))) unsigned int*)(Bg1 + k0),
        (__attribute__((address_space(3))) unsigned int*)BsW1, 16, 0, 0);
    __syncthreads();

    bf16x8 af[4], bfr[4];
#pragma unroll
    for (int i = 0; i < 4; i++) af[i] = *(const bf16x8*)(ArP + i * 16 * 32);
#pragma unroll
    for (int j = 0; j < 4; j++) bfr[j] = *(const bf16x8*)(BrP + j * 16 * 32);
#pragma unroll
    for (int i = 0; i < 4; i++)
#pragma unroll
      for (int j = 0; j < 4; j++)
        acc[i][j] = __builtin_amdgcn_mfma_f32_16x16x32_bf16(af[i], bfr[j],
                                                            acc[i][j], 0, 0, 0);
    __syncthreads();
  }

#pragma unroll
  for (int i = 0; i < 4; i++)
#pragma unroll
    for (int j = 0; j < 4; j++)
#pragma unroll
      for (int r = 0; r < 4; r++) {
        size_t row = m0 + wm + i * 16 + quad * 4 + r;
        size_t col = n0 + wn + j * 16 + l16;
        C[row * (size_t)ldc + col] = acc[i][j][r];
      }
}

extern "C" void kernel_launch(void* const* d_in, const int* in_sizes, int n_in,
                              void* d_out, int out_size, void* d_ws, size_t ws_size,
                              hipStream_t stream) {
  const float* q = (const float*)d_in[0];
  const float* k = (const float*)d_in[1];
  const float* v = (const float*)d_in[2];
  float* out = (float*)d_out;

  char* ws = (char*)d_ws;
  const size_t MB = 1024ull * 1024ull;
  unsigned short* qb     = (unsigned short*)(ws);
  unsigned short* kb     = (unsigned short*)(ws + 16 * MB);
  unsigned short* vbT    = (unsigned short*)(ws + 32 * MB);
  unsigned short* scores = (unsigned short*)(ws + 48 * MB);
  float*          scale  = (float*)(ws + 176 * MB);  // sumsq

  const int nqk = MROWS * DIN;

  // zero sumsq only (out is fully written by gemm2 plain stores now)
  zero_f32_kernel<<<(MROWS / 4 + 255) / 256, 256, 0, stream>>>(scale, MROWS / 4);

  cvt_kernel<<<nqk / 1024, 256, 0, stream>>>(q, qb, nqk);
  cvt_kernel<<<nqk / 1024, 256, 0, stream>>>(k, kb, nqk);
  transpose_cvt_kernel<<<dim3(DOUT / 32, NBANK / 32), dim3(32, 8), 0, stream>>>(
      v, vbT, NBANK, DOUT);

  gemm1_kernel<<<dim3(NBANK / 256, MROWS / 256), 512, 0, stream>>>(qb, kb, scores,
                                                                   scale);

  gelu_kernel<<<4096, 256, 0, stream>>>(scores, scale);

  gemm2_kernel<<<dim3(DOUT / 128, MROWS / 128), 256, 0, stream>>>(scores, vbT, out);
}

// Round 5
// 541.065 us; speedup vs baseline: 1.1348x; 1.0059x over previous
//
#include <hip/hip_runtime.h>
#include <hip/hip_bf16.h>
#include <math.h>

// q [8192,1024] f32, k [8192,1024] f32, v [8192,1024] f32
// scores = q@k^T; x = scores/||row|| * sqrt(8192); gated = gelu_exact(x); out = gated@v
//
// ws layout (~176 MiB):
//   [0,16M)    qb   bf16 8192x1024
//   [16M,32M)  kb   bf16 8192x1024
//   [32M,48M)  vbT  bf16 1024x8192
//   [48M,176M) scores/gated bf16 8192x8192 (in-place gelu)
//   [176M,+32K) sumsq f32 [8192]
//
// LDS bank swizzle (rule 21, both-sides XOR involution):
//   linear gload_lds dest; SOURCE 16B-slot pre-permuted slot^=(row>>1)&3;
//   READ slot XORed identically. Removes the 8-way/word bank aliasing of the
//   [row][32-short] layout (bank was 16*(row&1)+4*quad+w -> 8 banks only).

#define MROWS 8192
#define DIN   1024
#define NBANK 8192
#define DOUT  1024

typedef float  f32x4  __attribute__((ext_vector_type(4)));
typedef __bf16 bf16x8 __attribute__((ext_vector_type(8)));

__device__ __forceinline__ float bf2f(unsigned short u) {
  union { unsigned int i; float f; } x; x.i = ((unsigned int)u) << 16; return x.f;
}
__device__ __forceinline__ unsigned short f2bf(float f) {
  union { float f; unsigned int i; } x; x.f = f;
  unsigned int u = x.i;
  unsigned int r = (u + 0x7fffu + ((u >> 16) & 1u)) >> 16;  // RNE
  return (unsigned short)r;
}

// ---------------- fp32 -> bf16 convert ----------------
__global__ void cvt_kernel(const float* __restrict__ src,
                           unsigned short* __restrict__ dst, int n) {
  int i = (blockIdx.x * 256 + threadIdx.x) * 4;
  if (i >= n) return;
  float4 vv = *(const float4*)(src + i);
  ushort4 o;
  o.x = f2bf(vv.x); o.y = f2bf(vv.y); o.z = f2bf(vv.z); o.w = f2bf(vv.w);
  *(ushort4*)(dst + i) = o;
}

// ---------------- transpose + convert: src[R][C] f32 -> dst[C][R] bf16 ----------------
__global__ void transpose_cvt_kernel(const float* __restrict__ src,
                                     unsigned short* __restrict__ dst,
                                     int R, int C) {
  __shared__ float tile[32][33];
  int c0 = blockIdx.x * 32, r0 = blockIdx.y * 32;
  for (int i = threadIdx.y; i < 32; i += 8)
    tile[i][threadIdx.x] = src[(size_t)(r0 + i) * C + c0 + threadIdx.x];
  __syncthreads();
  for (int i = threadIdx.y; i < 32; i += 8)
    dst[(size_t)(c0 + i) * R + r0 + threadIdx.x] = f2bf(tile[threadIdx.x][i]);
}

// ---------------- zero fill (float4 granularity) ----------------
__global__ void zero_f32_kernel(float* __restrict__ p, int n4) {
  int i = blockIdx.x * 256 + threadIdx.x;
  if (i < n4) ((float4*)p)[i] = make_float4(0.f, 0.f, 0.f, 0.f);
}

// ============================================================================
// 256x256 4-phase GEMM core (gemm1), now with both-sides LDS XOR swizzle.
// ============================================================================

__device__ __forceinline__ void stage_half(const unsigned short* src, int ld,
                                           unsigned short* dstbase, int tid) {
  __builtin_amdgcn_global_load_lds(
      (const __attribute__((address_space(1))) unsigned int*)src,
      (__attribute__((address_space(3))) unsigned int*)(dstbase + tid * 8), 16, 0, 0);
  __builtin_amdgcn_global_load_lds(
      (const __attribute__((address_space(1))) unsigned int*)(src + (size_t)128 * ld),
      (__attribute__((address_space(3))) unsigned int*)(dstbase + 4096 + tid * 8), 16,
      0, 0);
}

__device__ __forceinline__ void read4(const unsigned short* base, bf16x8 f[4]) {
#pragma unroll
  for (int i = 0; i < 4; ++i) f[i] = *(const bf16x8*)(base + i * 512);
}

__device__ __forceinline__ void mfma16(const bf16x8 a[4], const bf16x8 b[4],
                                       f32x4 (&acc)[8][4], int mh) {
#pragma unroll
  for (int m = 0; m < 4; ++m)
#pragma unroll
    for (int n = 0; n < 4; ++n)
      acc[mh * 4 + m][n] = __builtin_amdgcn_mfma_f32_16x16x32_bf16(
          a[m], b[n], acc[mh * 4 + m][n], 0, 0, 0);
}

__device__ __forceinline__ void gemm_core(const unsigned short* __restrict__ Ap,
                                          const unsigned short* __restrict__ Bp,
                                          int lda, int ldb, int nkt,
                                          unsigned short* As, unsigned short* Bs,
                                          f32x4 (&acc)[8][4]) {
  const int tid  = threadIdx.x;
  const int lane = tid & 63;
  const int wm   = (tid >> 6) >> 2;  // 0..1
  const int wn   = (tid >> 6) & 3;   // 0..3
  const int quad = lane >> 4;
  const int l16  = lane & 15;
  // read-side swizzle: slot = quad ^ ((row>>1)&3); row strides are mult. of 4
  const int sw   = (l16 >> 1) & 3;
  const int aoff = (wm * 128 + l16) * 32 + (quad ^ sw) * 8;
  const int boff = (wn * 64 + l16) * 32 + (quad ^ sw) * 8;

  // source-side swizzle: thread (row=tid>>2, slot=tid&3) fetches global slot
  // (tid&3) ^ ((row>>1)&3); +128-row and +64-row offsets preserve (row>>1)&3.
  const int gslot = (tid & 3) ^ ((tid >> 3) & 3);
  const unsigned short* Ag = Ap + (size_t)(tid >> 2) * lda + gslot * 8;
  const unsigned short* Bg = Bp + (size_t)(tid >> 2) * ldb + gslot * 8;

#pragma unroll
  for (int i = 0; i < 8; ++i)
#pragma unroll
    for (int j = 0; j < 4; ++j) {
      f32x4 z = {0.f, 0.f, 0.f, 0.f};
      acc[i][j] = z;
    }

  stage_half(Ag, lda, As, tid);
  stage_half(Bg, ldb, Bs, tid);
  stage_half(Ag + 32, lda, As + 8192, tid);
  stage_half(Bg + 32, ldb, Bs + 8192, tid);
  asm volatile("s_waitcnt vmcnt(4)" ::: "memory");
  __builtin_amdgcn_s_barrier();

  for (int kt = 0; kt < nkt; ++kt) {
    const int cur = kt & 1, nx = cur ^ 1;
    const unsigned short* Ab = As + cur * 16384;
    const unsigned short* Bb = Bs + cur * 16384;
    unsigned short* Asn = As + nx * 16384;
    unsigned short* Bsn = Bs + nx * 16384;
    const bool pf = (kt + 1 < nkt);
    const int knext = (kt + 1) * 64;
    bf16x8 a[4], b[4];

    // ---- P0: (mh0, ks0) ----
    read4(Ab + aoff, a);
    read4(Bb + boff, b);
    if (pf) stage_half(Ag + knext, lda, Asn, tid);
    __builtin_amdgcn_s_barrier();
    asm volatile("s_waitcnt lgkmcnt(0)" ::: "memory");
    __builtin_amdgcn_sched_barrier(0);
    __builtin_amdgcn_s_setprio(1);
    mfma16(a, b, acc, 0);
    __builtin_amdgcn_s_setprio(0);
    __builtin_amdgcn_s_barrier();

    // ---- P1: (mh1, ks0) ----
    read4(Ab + aoff + 2048, a);
    if (pf) stage_half(Bg + knext, ldb, Bsn, tid);
    __builtin_amdgcn_s_barrier();
    asm volatile("s_waitcnt lgkmcnt(0)" ::: "memory");
    __builtin_amdgcn_sched_barrier(0);
    __builtin_amdgcn_s_setprio(1);
    mfma16(a, b, acc, 1);
    __builtin_amdgcn_s_setprio(0);
    if (pf)
      asm volatile("s_waitcnt vmcnt(4)" ::: "memory");
    else
      asm volatile("s_waitcnt vmcnt(0)" ::: "memory");
    __builtin_amdgcn_s_barrier();

    // ---- P2: (mh1, ks1) ----
    read4(Ab + 8192 + aoff + 2048, a);
    read4(Bb + 8192 + boff, b);
    if (pf) stage_half(Ag + knext + 32, lda, Asn + 8192, tid);
    __builtin_amdgcn_s_barrier();
    asm volatile("s_waitcnt lgkmcnt(0)" ::: "memory");
    __builtin_amdgcn_sched_barrier(0);
    __builtin_amdgcn_s_setprio(1);
    mfma16(a, b, acc, 1);
    __builtin_amdgcn_s_setprio(0);
    __builtin_amdgcn_s_barrier();

    // ---- P3: (mh0, ks1) ----
    read4(Ab + 8192 + aoff, a);
    if (pf) stage_half(Bg + knext + 32, ldb, Bsn + 8192, tid);
    __builtin_amdgcn_s_barrier();
    asm volatile("s_waitcnt lgkmcnt(0)" ::: "memory");
    __builtin_amdgcn_sched_barrier(0);
    __builtin_amdgcn_s_setprio(1);
    mfma16(a, b, acc, 0);
    __builtin_amdgcn_s_setprio(0);
    if (pf) asm volatile("s_waitcnt vmcnt(4)" ::: "memory");
    __builtin_amdgcn_s_barrier();
  }
}

// ---------------- GEMM1: scores = qb @ kb^T (bf16 out) + row sumsq atomics ----------
__global__ __launch_bounds__(512) void gemm1_kernel(
    const unsigned short* __restrict__ A, const unsigned short* __restrict__ B,
    unsigned short* __restrict__ C, float* __restrict__ sumsq) {
  __shared__ unsigned short As[2 * 16384];
  __shared__ unsigned short Bs[2 * 16384];

  const int flat = blockIdx.y * gridDim.x + blockIdx.x;
  const int nwg  = gridDim.x * gridDim.y;
  const int swz  = (flat & 7) * (nwg >> 3) + (flat >> 3);
  const size_t m0 = (size_t)(swz / gridDim.x) * 256;
  const size_t n0 = (size_t)(swz % gridDim.x) * 256;

  f32x4 acc[8][4];
  gemm_core(A + m0 * DIN, B + n0 * DIN, DIN, DIN, DIN / 64, As, Bs, acc);

  const int tid  = threadIdx.x;
  const int lane = tid & 63;
  const int wm   = (tid >> 6) >> 2;
  const int wn   = (tid >> 6) & 3;
  const int quad = lane >> 4;
  const int l16  = lane & 15;

#pragma unroll
  for (int mf = 0; mf < 8; ++mf)
#pragma unroll
    for (int r = 0; r < 4; ++r) {
      size_t row = m0 + wm * 128 + mf * 16 + quad * 4 + r;
      float s = 0.f;
#pragma unroll
      for (int nf = 0; nf < 4; ++nf) {
        float val = acc[mf][nf][r];
        s += val * val;
        C[row * (size_t)NBANK + n0 + wn * 64 + nf * 16 + l16] = f2bf(val);
      }
      s += __shfl_xor(s, 1);
      s += __shfl_xor(s, 2);
      s += __shfl_xor(s, 4);
      s += __shfl_xor(s, 8);
      if (l16 == 0) atomicAdd(&sumsq[row], s);
    }
}

// ---------------- in-place exact GELU(x * sqrt(N/sumsq[row])) ----------------
__global__ void gelu_kernel(unsigned short* __restrict__ S,
                            const float* __restrict__ sumsq) {
  const size_t total = (size_t)MROWS * NBANK / 8;  // uint4 units
  for (size_t u = (size_t)blockIdx.x * 256 + threadIdx.x; u < total;
       u += (size_t)gridDim.x * 256) {
    size_t idx = u * 8;
    int row = (int)(idx >> 13);
    float sc = sqrtf((float)NBANK / sumsq[row]);
    uint4 vv = *(const uint4*)(S + idx);
    unsigned int w[4] = {vv.x, vv.y, vv.z, vv.w};
#pragma unroll
    for (int e = 0; e < 4; e++) {
      float x0 = bf2f((unsigned short)(w[e] & 0xffffu)) * sc;
      float x1 = bf2f((unsigned short)(w[e] >> 16)) * sc;
      float g0 = 0.5f * x0 * (1.0f + erff(x0 * 0.70710678118654752f));
      float g1 = 0.5f * x1 * (1.0f + erff(x1 * 0.70710678118654752f));
      w[e] = (unsigned int)f2bf(g0) | ((unsigned int)f2bf(g1) << 16);
    }
    uint4 o; o.x = w[0]; o.y = w[1]; o.z = w[2]; o.w = w[3];
    *(uint4*)(S + idx) = o;
  }
}

// ---------------- GEMM2: out = gated @ vbT^T, 128x128 tile, NO split-K --------------
// m97-class structure + the same both-sides LDS XOR swizzle.
__global__ __launch_bounds__(256, 4) void gemm2_kernel(
    const unsigned short* __restrict__ A,   // gated [8192][8192]
    const unsigned short* __restrict__ B,   // vbT   [1024][8192]
    float* __restrict__ C) {                // out   [8192][1024]
  __shared__ unsigned short As[128 * 32];
  __shared__ unsigned short Bs[128 * 32];
  const int K = NBANK, ldc = DOUT;

  const int tid  = threadIdx.x;
  const int lane = tid & 63;
  const int wave = tid >> 6;
  const int wm   = (wave >> 1) * 64;
  const int wn   = (wave & 1) * 64;
  const int quad = lane >> 4;
  const int l16  = lane & 15;

  // XCD swizzle: nwg = 8*64 = 512, %8==0.
  const int flat = blockIdx.y * gridDim.x + blockIdx.x;
  const int nwg  = gridDim.x * gridDim.y;
  const int swz  = (flat & 7) * (nwg >> 3) + (flat >> 3);
  const size_t m0 = (size_t)(swz / gridDim.x) * 128;
  const size_t n0 = (size_t)(swz % gridDim.x) * 128;

  const int srow = tid >> 2;
  // source-side slot swizzle (rows srow and srow+64 share (row>>1)&3)
  const int scol = (((tid & 3) ^ ((tid >> 3) & 3))) * 8;
  const unsigned short* Ag0 = A + (m0 + srow) * (size_t)K + scol;
  const unsigned short* Ag1 = A + (m0 + srow + 64) * (size_t)K + scol;
  const unsigned short* Bg0 = B + (n0 + srow) * (size_t)K + scol;
  const unsigned short* Bg1 = B + (n0 + srow + 64) * (size_t)K + scol;

  unsigned short* AsW0 = As + tid * 8;
  unsigned short* AsW1 = As + 64 * 32 + tid * 8;
  unsigned short* BsW0 = Bs + tid * 8;
  unsigned short* BsW1 = Bs + 64 * 32 + tid * 8;

  // read-side swizzle: slot = quad ^ ((l16>>1)&3); wm/wn and i*16 row strides
  // are multiples of 4 rows so the XOR folds into the base.
  const int sw = (l16 >> 1) & 3;
  const unsigned short* ArP = As + (wm + l16) * 32 + (quad ^ sw) * 8;
  const unsigned short* BrP = Bs + (wn + l16) * 32 + (quad ^ sw) * 8;

  f32x4 acc[4][4];
#pragma unroll
  for (int i = 0; i < 4; i++)
#pragma unroll
    for (int j = 0; j < 4; j++) {
      f32x4 z = {0.f, 0.f, 0.f, 0.f};
      acc[i][j] = z;
    }

  for (int k0 = 0; k0 < K; k0 += 32) {
    __builtin_amdgcn_global_load_lds(
        (const __attribute__((address_space(1))) unsigned int*)(Ag0 + k0),
        (__attribute__((address_space(3))) unsigned int*)AsW0, 16, 0, 0);
    __builtin_amdgcn_global_load_lds(
        (const __attribute__((address_space(1))) unsigned int*)(Ag1 + k0),
        (__attribute__((address_space(3))) unsigned int*)AsW1, 16, 0, 0);
    __builtin_amdgcn_global_load_lds(
        (const __attribute__((address_space(1))) unsigned int*)(Bg0 + k0),
        (__attribute__((address_space(3))) unsigned int*)BsW0, 16, 0, 0);
    __builtin_amdgcn_global_load_lds(
        (const __attribute__((address_space(1))) unsigned int*)(Bg1 + k0),
        (__attribute__((address_space(3))) unsigned int*)BsW1, 16, 0, 0);
    __syncthreads();

    bf16x8 af[4], bfr[4];
#pragma unroll
    for (int i = 0; i < 4; i++) af[i] = *(const bf16x8*)(ArP + i * 16 * 32);
#pragma unroll
    for (int j = 0; j < 4; j++) bfr[j] = *(const bf16x8*)(BrP + j * 16 * 32);
#pragma unroll
    for (int i = 0; i < 4; i++)
#pragma unroll
      for (int j = 0; j < 4; j++)
        acc[i][j] = __builtin_amdgcn_mfma_f32_16x16x32_bf16(af[i], bfr[j],
                                                            acc[i][j], 0, 0, 0);
    __syncthreads();
  }

#pragma unroll
  for (int i = 0; i < 4; i++)
#pragma unroll
    for (int j = 0; j < 4; j++)
#pragma unroll
      for (int r = 0; r < 4; r++) {
        size_t row = m0 + wm + i * 16 + quad * 4 + r;
        size_t col = n0 + wn + j * 16 + l16;
        C[row * (size_t)ldc + col] = acc[i][j][r];
      }
}

extern "C" void kernel_launch(void* const* d_in, const int* in_sizes, int n_in,
                              void* d_out, int out_size, void* d_ws, size_t ws_size,
                              hipStream_t stream) {
  const float* q = (const float*)d_in[0];
  const float* k = (const float*)d_in[1];
  const float* v = (const float*)d_in[2];
  float* out = (float*)d_out;

  char* ws = (char*)d_ws;
  const size_t MB = 1024ull * 1024ull;
  unsigned short* qb     = (unsigned short*)(ws);
  unsigned short* kb     = (unsigned short*)(ws + 16 * MB);
  unsigned short* vbT    = (unsigned short*)(ws + 32 * MB);
  unsigned short* scores = (unsigned short*)(ws + 48 * MB);
  float*          scale  = (float*)(ws + 176 * MB);  // sumsq

  const int nqk = MROWS * DIN;

  // zero sumsq only (out is fully written by gemm2 plain stores)
  zero_f32_kernel<<<(MROWS / 4 + 255) / 256, 256, 0, stream>>>(scale, MROWS / 4);

  cvt_kernel<<<nqk / 1024, 256, 0, stream>>>(q, qb, nqk);
  cvt_kernel<<<nqk / 1024, 256, 0, stream>>>(k, kb, nqk);
  transpose_cvt_kernel<<<dim3(DOUT / 32, NBANK / 32), dim3(32, 8), 0, stream>>>(
      v, vbT, NBANK, DOUT);

  gemm1_kernel<<<dim3(NBANK / 256, MROWS / 256), 512, 0, stream>>>(qb, kb, scores,
                                                                   scale);

  gelu_kernel<<<4096, 256, 0, stream>>>(scores, scale);

  gemm2_kernel<<<dim3(DOUT / 128, MROWS / 128), 256, 0, stream>>>(scores, vbT, out);
}